// Round 1
// baseline (832.448 us; speedup 1.0000x reference)
//
#include <hip/hip_runtime.h>
#include <stdint.h>

// Problem constants (reference: B=128, S=1024, D=1024)
#define BB 128
#define SS 1024
#define DD 1024

typedef __attribute__((ext_vector_type(4))) float f32x4;
typedef __attribute__((ext_vector_type(8))) short s16x8;

// round-half-up fp32->bf16 pair pack: 3 VALU per 2 elements
__device__ __forceinline__ unsigned pack_bf(float lo, float hi) {
    unsigned ul = __builtin_bit_cast(unsigned, lo) + 0x8000u;
    unsigned uh = __builtin_bit_cast(unsigned, hi) + 0x8000u;
    return __builtin_amdgcn_perm(uh, ul, 0x07060302u);
}

// ---------------- kernel 1: lens[b] = clip(sum(mask[b,:]),1), num_nodes = sum(lens) -------------
__global__ __launch_bounds__(256) void lens_kernel(const int* __restrict__ mask,
                                                   int* __restrict__ nn_lens) {
    const int b = blockIdx.x;
    const int t = threadIdx.x;
    const int* row = mask + b * SS;
    int s = row[t] + row[t + 256] + row[t + 512] + row[t + 768];
    #pragma unroll
    for (int off = 32; off > 0; off >>= 1) s += __shfl_down(s, off, 64);
    __shared__ int red[4];
    const int wid = t >> 6, lane = t & 63;
    if (lane == 0) red[wid] = s;
    __syncthreads();
    if (t == 0) {
        int tot = red[0] + red[1] + red[2] + red[3];
        if (tot < 1) tot = 1;
        nn_lens[1 + b] = tot;
        atomicAdd(&nn_lens[0], tot);
    }
}

// ---------------- kernel 1b: ctx fp32 -> bf16, MFMA-B-fragment layout Bp[kc][col][kk] ----------
// A wave's b-frag load (col = j*16+ln15, k = kc*32 + quad*8 .. +8) becomes 1 KB contiguous.
__global__ __launch_bounds__(256) void bconv_kernel(const float* __restrict__ ctx,
                                                    unsigned short* __restrict__ Bp) {
    const int c = blockIdx.x;        // 0..127 (graph / col index)
    const int t = threadIdx.x;       // 0..255, 4 consecutive k each
    const int k = t << 2;
    f32x4 v = *(const f32x4*)(ctx + (size_t)c * DD + k);
    uint2 p;
    p.x = pack_bf(v.x, v.y);
    p.y = pack_bf(v.z, v.w);
    *(uint2*)(Bp + (((size_t)(k >> 5) * BB + c) << 5) + (k & 31)) = p;
}

// ---------------- kernel 2: LDS-free, barrier-free GEMM + fused JSD epilogue -------------------
// N=128 fits a wave's register tile: each wave owns 32 rows x 128 cols (acc[2][8], 64 VGPRs).
// A fragments are wave-private -> load global->reg with 1-deep prefetch, pack in-reg.
// B is pre-converted bf16 (256 KB total, L2-resident) read directly as fragments.
// 4096 independent waves, no __syncthreads in the K-loop -> latency hidden by TLP + prefetch.
__global__ __launch_bounds__(256, 3) void mi_kernel(const float* __restrict__ A,   // [B*S, D] fp32
                                                    const unsigned short* __restrict__ Bp,
                                                    const int* __restrict__ nn_lens,
                                                    float* __restrict__ out) {
    const int tid  = threadIdx.x;
    const int lane = tid & 63;
    const int wid  = tid >> 6;
    const int ln15 = lane & 15;
    const int quad = lane >> 4;

    const int blk   = blockIdx.x;
    const int b_idx = blk >> 3;                      // graph index (S/128 = 8 blocks per graph)
    const int s_w   = ((blk & 7) << 7) + (wid << 5); // wave's first sequence row

    const size_t m0 = ((size_t)blk << 7) + (size_t)(wid << 5);
    const float* A0 = A + (m0 + ln15) * DD + (quad << 3);        // i=0 rows
    const float* A1 = A0 + (size_t)16 * DD;                      // i=1 rows
    const unsigned short* Bq = Bp + (ln15 << 5) + (quad << 3);   // + kc*4096 + j*512

    f32x4 acc[2][8];
    #pragma unroll
    for (int i = 0; i < 2; i++)
        #pragma unroll
        for (int j = 0; j < 8; j++) acc[i][j] = (f32x4)0.f;

    // prologue: prefetch kc=0 A raw (8 consecutive floats per lane per row-block)
    f32x4 c00 = *(const f32x4*)(A0);
    f32x4 c01 = *(const f32x4*)(A0 + 4);
    f32x4 c10 = *(const f32x4*)(A1);
    f32x4 c11 = *(const f32x4*)(A1 + 4);

    #pragma unroll 2
    for (int kc = 0; kc < 32; kc++) {
        // issue next-iteration A loads first (HBM latency hides under pack+MFMA of current kc)
        const int kn = (kc < 31) ? ((kc + 1) << 5) : 0;   // clamp: no OOB on last iter
        f32x4 n00 = *(const f32x4*)(A0 + kn);
        f32x4 n01 = *(const f32x4*)(A0 + kn + 4);
        f32x4 n10 = *(const f32x4*)(A1 + kn);
        f32x4 n11 = *(const f32x4*)(A1 + kn + 4);

        // B fragments for this kc: 8 x 16B coalesced loads, L1/L2-hot (256 KB total working set)
        const unsigned short* Bk = Bq + ((size_t)kc << 12);   // kc * 128 cols * 32 k
        s16x8 bf[8];
        #pragma unroll
        for (int j = 0; j < 8; j++)
            bf[j] = *(const s16x8*)(Bk + (j << 9));

        // in-register fp32 -> bf16 pack of current A (16 packs = 48 VALU)
        uint4 p0, p1;
        p0.x = pack_bf(c00.x, c00.y);  p0.y = pack_bf(c00.z, c00.w);
        p0.z = pack_bf(c01.x, c01.y);  p0.w = pack_bf(c01.z, c01.w);
        p1.x = pack_bf(c10.x, c10.y);  p1.y = pack_bf(c10.z, c10.w);
        p1.z = pack_bf(c11.x, c11.y);  p1.w = pack_bf(c11.z, c11.w);
        s16x8 af0 = __builtin_bit_cast(s16x8, p0);
        s16x8 af1 = __builtin_bit_cast(s16x8, p1);

        #pragma unroll
        for (int j = 0; j < 8; j++) {
            acc[0][j] = __builtin_amdgcn_mfma_f32_16x16x32_bf16(af0, bf[j], acc[0][j], 0, 0, 0);
            acc[1][j] = __builtin_amdgcn_mfma_f32_16x16x32_bf16(af1, bf[j], acc[1][j], 0, 0, 0);
        }

        c00 = n00; c01 = n01; c10 = n10; c11 = n11;
    }

    // ---- fused epilogue: JSD terms, masked ----
    const int num_nodes = nn_lens[0];
    const int len_b     = nn_lens[1 + b_idx];
    const float LOG2f = 0.6931471805599453f;

    float pos_sum = 0.f, neg_sum = 0.f;
    #pragma unroll
    for (int i = 0; i < 2; i++) {
        #pragma unroll
        for (int r = 0; r < 4; r++) {
            const int s = s_w + (i << 4) + (quad << 2) + r;      // C/D row = quad*4 + reg
            const bool valid = (s < len_b);
            #pragma unroll
            for (int j = 0; j < 8; j++) {
                const int n = (j << 4) + ln15;                   // C/D col = lane&15
                const float x = acc[i][j][r];
                const float e  = __expf(-fabsf(x));
                const float sp = fmaxf(-x, 0.f) + __logf(1.f + e);   // softplus(-x), stable
                if (valid) {
                    if (n == b_idx) pos_sum += LOG2f - sp;           // Ep
                    else            neg_sum += sp + x - LOG2f;       // Eq
                }
            }
        }
    }

    // block reduction + one atomic per block
    #pragma unroll
    for (int off = 32; off > 0; off >>= 1) {
        pos_sum += __shfl_down(pos_sum, off, 64);
        neg_sum += __shfl_down(neg_sum, off, 64);
    }
    __shared__ float red[8];
    if (lane == 0) { red[wid] = pos_sum; red[4 + wid] = neg_sum; }
    __syncthreads();
    if (tid == 0) {
        const float p  = red[0] + red[1] + red[2] + red[3];
        const float ng = red[4] + red[5] + red[6] + red[7];
        const float nn = (float)num_nodes;
        atomicAdd(out, ng / (nn * (float)(BB - 1)) - p / nn);
    }
}

extern "C" void kernel_launch(void* const* d_in, const int* in_sizes, int n_in,
                              void* d_out, int out_size, void* d_ws, size_t ws_size,
                              hipStream_t stream) {
    const float* seq  = (const float*)d_in[0];   // [128,1024,1024] fp32
    const float* ctx  = (const float*)d_in[1];   // [128,1024] fp32
    const int*   mask = (const int*)d_in[2];     // [128,1024] int32
    int* nn_lens = (int*)d_ws;                            // [0]=num_nodes, [1..128]=lens
    unsigned short* Bp = (unsigned short*)((char*)d_ws + 1024);  // 256 KB bf16 ctx fragments

    hipMemsetAsync(d_out, 0, sizeof(float), stream);
    hipMemsetAsync(d_ws, 0, sizeof(int), stream);

    lens_kernel<<<BB, 256, 0, stream>>>(mask, nn_lens);
    bconv_kernel<<<BB, 256, 0, stream>>>(ctx, Bp);
    mi_kernel<<<(BB * SS) / 128, 256, 0, stream>>>(seq, Bp, nn_lens, (float*)d_out);
}

// Round 2
// 797.189 us; speedup vs baseline: 1.0442x; 1.0442x over previous
//
#include <hip/hip_runtime.h>
#include <stdint.h>

// Problem constants (reference: B=128, S=1024, D=1024)
#define BB 128
#define SS 1024
#define DD 1024

typedef __attribute__((ext_vector_type(4))) float f32x4;
typedef __attribute__((ext_vector_type(8))) short s16x8;

// round-half-up fp32->bf16 pair pack: 3 VALU per 2 elements
__device__ __forceinline__ unsigned pack_bf(float lo, float hi) {
    unsigned ul = __builtin_bit_cast(unsigned, lo) + 0x8000u;
    unsigned uh = __builtin_bit_cast(unsigned, hi) + 0x8000u;
    return __builtin_amdgcn_perm(uh, ul, 0x07060302u);
}

// ---------------- kernel 1: lens[b] = clip(sum(mask[b,:]),1), num_nodes = sum(lens) -------------
__global__ __launch_bounds__(256) void lens_kernel(const int* __restrict__ mask,
                                                   int* __restrict__ nn_lens) {
    const int b = blockIdx.x;
    const int t = threadIdx.x;
    const int* row = mask + b * SS;
    int s = row[t] + row[t + 256] + row[t + 512] + row[t + 768];
    #pragma unroll
    for (int off = 32; off > 0; off >>= 1) s += __shfl_down(s, off, 64);
    __shared__ int red[4];
    const int wid = t >> 6, lane = t & 63;
    if (lane == 0) red[wid] = s;
    __syncthreads();
    if (t == 0) {
        int tot = red[0] + red[1] + red[2] + red[3];
        if (tot < 1) tot = 1;
        nn_lens[1 + b] = tot;
        atomicAdd(&nn_lens[0], tot);
    }
}

// ---------------- kernel 1b: ctx fp32 -> bf16, MFMA-B-fragment layout Bp[kc][col][kk] ----------
__global__ __launch_bounds__(256) void bconv_kernel(const float* __restrict__ ctx,
                                                    unsigned short* __restrict__ Bp) {
    const int c = blockIdx.x;        // 0..127 (graph / col index)
    const int t = threadIdx.x;       // 0..255, 4 consecutive k each
    const int k = t << 2;
    f32x4 v = *(const f32x4*)(ctx + (size_t)c * DD + k);
    uint2 p;
    p.x = pack_bf(v.x, v.y);
    p.y = pack_bf(v.z, v.w);
    *(uint2*)(Bp + (((size_t)(k >> 5) * BB + c) << 5) + (k & 31)) = p;
}

// ---------------- kernel 2: LDS-free GEMM + fused JSD epilogue, queue-ordered prefetch ---------
// Each wave owns 16 rows x 128 cols (acc[8] = 32 VGPRs). A-frags are wave-private: a lane's
// 32B fp32 load IS its MFMA A-fragment slab (row=ln15, k=quad*8..+8) -> no LDS, no shuffles.
// VMEM completion is an IN-ORDER queue: waiting for bf(kc) waits for everything older.
// Therefore per-iteration issue order is  B(kc+1) -> A(kc+2) -> pack A(kc) -> MFMA with B(kc):
//   - MFMA's wait target B(kc) was issued one full iteration ago (L1-hot, covered)
//   - nothing younger than B(kc) is needed, so A(kc+1)/A(kc+2) stay in flight across the wait
//   - A gets 2 iterations of slack (~3 waves/SIMD x ~250 cyc) vs ~900 cyc HBM latency
__global__ __launch_bounds__(256, 3) void mi_kernel(const float* __restrict__ A,   // [B*S, D] fp32
                                                    const unsigned short* __restrict__ Bp,
                                                    const int* __restrict__ nn_lens,
                                                    float* __restrict__ out) {
    const int tid  = threadIdx.x;
    const int lane = tid & 63;
    const int wid  = tid >> 6;
    const int ln15 = lane & 15;
    const int quad = lane >> 4;

    const int blk   = blockIdx.x;                    // 2048 blocks, 64 rows each
    const int b_idx = blk >> 4;                      // graph index (1024/64 = 16 blocks/graph)
    const int s_w   = ((blk & 15) << 6) + (wid << 4);// wave's first sequence row within graph

    const size_t m0 = ((size_t)blk << 6) + (size_t)(wid << 4);
    const float* A0 = A + (m0 + ln15) * DD + (quad << 3);        // this lane's row+k slab
    const unsigned short* Bq = Bp + (ln15 << 5) + (quad << 3);

    f32x4 acc[8];
    #pragma unroll
    for (int j = 0; j < 8; j++) acc[j] = (f32x4)0.f;

    f32x4 aC0, aC1, aN10, aN11, aN20, aN21;
    s16x8 bC[8], bN[8];

    // prologue — queue order: A(0), B(0), A(1)
    aC0 = *(const f32x4*)(A0);
    aC1 = *(const f32x4*)(A0 + 4);
    #pragma unroll
    for (int j = 0; j < 8; j++) bC[j] = *(const s16x8*)(Bq + (j << 9));
    aN10 = *(const f32x4*)(A0 + 32);
    aN11 = *(const f32x4*)(A0 + 36);

    #pragma unroll 4
    for (int kc = 0; kc < 32; kc++) {
        // 1) B(kc+1): 8 x 16B, L1/L2-hot (wrap at the end, result discarded)
        const unsigned short* Bn = Bq + ((size_t)((kc + 1) & 31) << 12);
        #pragma unroll
        for (int j = 0; j < 8; j++) bN[j] = *(const s16x8*)(Bn + (j << 9));

        // 2) A(kc+2): 2 x 16B HBM (clamped at the tail, result discarded)
        const int ka = ((kc + 2) < 32 ? (kc + 2) : 0) << 5;
        aN20 = *(const f32x4*)(A0 + ka);
        aN21 = *(const f32x4*)(A0 + ka + 4);

        // 3) pack A(kc) -> bf16 fragment (A(kc) is 2 iterations old: no stall)
        uint4 p;
        p.x = pack_bf(aC0.x, aC0.y);  p.y = pack_bf(aC0.z, aC0.w);
        p.z = pack_bf(aC1.x, aC1.y);  p.w = pack_bf(aC1.z, aC1.w);
        s16x8 af = __builtin_bit_cast(s16x8, p);

        // 4) MFMA with B(kc) (issued last iteration; waiting for it leaves A(kc+1,2) in flight)
        #pragma unroll
        for (int j = 0; j < 8; j++)
            acc[j] = __builtin_amdgcn_mfma_f32_16x16x32_bf16(af, bC[j], acc[j], 0, 0, 0);

        // rotate (full SSA-renamed under unroll)
        aC0 = aN10; aC1 = aN11; aN10 = aN20; aN11 = aN21;
        #pragma unroll
        for (int j = 0; j < 8; j++) bC[j] = bN[j];
    }

    // ---- fused epilogue: JSD terms, masked ----
    const int num_nodes = nn_lens[0];
    const int len_b     = nn_lens[1 + b_idx];
    const float LOG2f = 0.6931471805599453f;

    float pos_sum = 0.f, neg_sum = 0.f;
    #pragma unroll
    for (int r = 0; r < 4; r++) {
        const int s = s_w + (quad << 2) + r;          // C/D row = quad*4 + reg
        const bool valid = (s < len_b);
        #pragma unroll
        for (int j = 0; j < 8; j++) {
            const int n = (j << 4) + ln15;            // C/D col = lane&15
            const float x = acc[j][r];
            const float e  = __expf(-fabsf(x));
            const float sp = fmaxf(-x, 0.f) + __logf(1.f + e);   // softplus(-x), stable
            if (valid) {
                if (n == b_idx) pos_sum += LOG2f - sp;           // Ep
                else            neg_sum += sp + x - LOG2f;       // Eq
            }
        }
    }

    // block reduction + one atomic per block
    #pragma unroll
    for (int off = 32; off > 0; off >>= 1) {
        pos_sum += __shfl_down(pos_sum, off, 64);
        neg_sum += __shfl_down(neg_sum, off, 64);
    }
    __shared__ float red[8];
    if (lane == 0) { red[wid] = pos_sum; red[4 + wid] = neg_sum; }
    __syncthreads();
    if (tid == 0) {
        const float p  = red[0] + red[1] + red[2] + red[3];
        const float ng = red[4] + red[5] + red[6] + red[7];
        const float nn = (float)num_nodes;
        atomicAdd(out, ng / (nn * (float)(BB - 1)) - p / nn);
    }
}

extern "C" void kernel_launch(void* const* d_in, const int* in_sizes, int n_in,
                              void* d_out, int out_size, void* d_ws, size_t ws_size,
                              hipStream_t stream) {
    const float* seq  = (const float*)d_in[0];   // [128,1024,1024] fp32
    const float* ctx  = (const float*)d_in[1];   // [128,1024] fp32
    const int*   mask = (const int*)d_in[2];     // [128,1024] int32
    int* nn_lens = (int*)d_ws;                            // [0]=num_nodes, [1..128]=lens
    unsigned short* Bp = (unsigned short*)((char*)d_ws + 1024);  // 256 KB bf16 ctx fragments

    hipMemsetAsync(d_out, 0, sizeof(float), stream);
    hipMemsetAsync(d_ws, 0, sizeof(int), stream);

    lens_kernel<<<BB, 256, 0, stream>>>(mask, nn_lens);
    bconv_kernel<<<BB, 256, 0, stream>>>(ctx, Bp);
    mi_kernel<<<(BB * SS) / 64, 256, 0, stream>>>(seq, Bp, nn_lens, (float*)d_out);
}

// Round 3
// 730.056 us; speedup vs baseline: 1.1403x; 1.0920x over previous
//
#include <hip/hip_runtime.h>
#include <stdint.h>

// Problem constants (reference: B=128, S=1024, D=1024)
#define BB 128
#define SS 1024
#define DD 1024
#define MT 128          // M-tile per block
#define BK 64           // K-chunk per iteration
#define LDT 72          // padded LDS row stride in shorts (144 B: spreads b128 reads over all banks)

typedef __attribute__((ext_vector_type(4))) float f32x4;
typedef __attribute__((ext_vector_type(8))) short s16x8;

// round-half-up fp32->bf16 pair pack: 3 VALU per 2 elements
__device__ __forceinline__ unsigned pack_bf(float lo, float hi) {
    unsigned ul = __builtin_bit_cast(unsigned, lo) + 0x8000u;
    unsigned uh = __builtin_bit_cast(unsigned, hi) + 0x8000u;
    return __builtin_amdgcn_perm(uh, ul, 0x07060302u);
}

// ---------------- kernel 1: lens[b] = clip(sum(mask[b,:]),1), num_nodes = sum(lens) -------------
__global__ __launch_bounds__(256) void lens_kernel(const int* __restrict__ mask,
                                                   int* __restrict__ nn_lens) {
    const int b = blockIdx.x;
    const int t = threadIdx.x;
    const int* row = mask + b * SS;
    int s = row[t] + row[t + 256] + row[t + 512] + row[t + 768];
    #pragma unroll
    for (int off = 32; off > 0; off >>= 1) s += __shfl_down(s, off, 64);
    __shared__ int red[4];
    const int wid = t >> 6, lane = t & 63;
    if (lane == 0) red[wid] = s;
    __syncthreads();
    if (t == 0) {
        int tot = red[0] + red[1] + red[2] + red[3];
        if (tot < 1) tot = 1;
        nn_lens[1 + b] = tot;
        atomicAdd(&nn_lens[0], tot);
    }
}

// ---------------- kernel 1b: ctx fp32 -> bf16 row-major [128][1024] (256 KB, L2-resident) ------
__global__ __launch_bounds__(256) void bconv_kernel(const float* __restrict__ ctx,
                                                    unsigned short* __restrict__ ctx_bf) {
    const int c = blockIdx.x;        // 0..127 (graph index)
    const int t = threadIdx.x;       // 0..255, 4 consecutive k each
    const int k = t << 2;
    f32x4 v = *(const f32x4*)(ctx + (size_t)c * DD + k);
    uint2 p;
    p.x = pack_bf(v.x, v.y);
    p.y = pack_bf(v.z, v.w);
    *(uint2*)(ctx_bf + (size_t)c * DD + k) = p;
}

// ---------------- kernel 2: GEMM (bf16 MFMA) + softplus epilogue + masked reduction -------------
// Proven round-0 structure (LDS staged, 2-barrier, (256,2)); only change: B side reads the
// pre-converted bf16 ctx (1 s16x8 load, 0 packs per pass vs 2 f32x4 + 4 packs) and B global
// traffic per block halves (512->256 KB, L2-hot).
__global__ __launch_bounds__(256, 2) void mi_kernel(const float* __restrict__ A,   // [B*S, D] fp32
                                                    const unsigned short* __restrict__ Bbf, // [B, D] bf16
                                                    const int* __restrict__ nn_lens,
                                                    float* __restrict__ out) {
    __shared__ short lds[2 * MT * LDT];
    short* As = lds;
    short* Bs = lds + MT * LDT;

    const int tid  = threadIdx.x;
    const int lane = tid & 63;
    const int wid  = tid >> 6;
    const int wm   = (wid >> 1) * 64;   // wave M offset within tile
    const int wn   = (wid & 1) * 64;    // wave N offset within tile
    const int ln15 = lane & 15;
    const int quad = lane >> 4;

    const int blk    = blockIdx.x;
    const size_t m0  = (size_t)blk * MT;
    const int b_idx  = blk >> 3;          // graph index of this block's rows (S/MT = 8)
    const int s_base = (blk & 7) * MT;    // sequence offset of row 0

    // staging: thread handles 8 consecutive elements -> 1 ds_write_b128
    const int srow = tid >> 3;   // 0..31 (4 passes of 32 rows cover 128)
    const int schk = tid & 7;    // 8-element chunk within a 64-k slab

    const float* Abase          = A   + (m0 + srow) * (size_t)DD + schk * 8;
    const unsigned short* Bbase = Bbf + (size_t)srow * DD + schk * 8;
    short* As_w = As + srow * LDT + schk * 8;
    short* Bs_w = Bs + srow * LDT + schk * 8;

    f32x4 acc[4][4];
    #pragma unroll
    for (int i = 0; i < 4; i++)
        #pragma unroll
        for (int j = 0; j < 4; j++) acc[i][j] = (f32x4)0.f;

    for (int kt = 0; kt < DD / BK; kt++) {
        const int k0 = kt * BK;
        #pragma unroll
        for (int p = 0; p < 4; p++) {
            const float* ga = Abase + (size_t)(p * 32) * DD + k0;
            f32x4 a0 = *(const f32x4*)(ga);
            f32x4 a1 = *(const f32x4*)(ga + 4);
            s16x8 bv = *(const s16x8*)(Bbase + (size_t)(p * 32) * DD + k0);
            uint4 pa;
            pa.x = pack_bf(a0.x, a0.y);  pa.y = pack_bf(a0.z, a0.w);
            pa.z = pack_bf(a1.x, a1.y);  pa.w = pack_bf(a1.z, a1.w);
            *(uint4*)(As_w + p * 32 * LDT) = pa;
            *(s16x8*)(Bs_w + p * 32 * LDT) = bv;
        }
        __syncthreads();
        #pragma unroll
        for (int ks = 0; ks < 2; ks++) {
            const int ko = ks * 32 + quad * 8;
            s16x8 af[4], bf[4];
            #pragma unroll
            for (int i = 0; i < 4; i++)
                af[i] = *(const s16x8*)(As + (wm + i * 16 + ln15) * LDT + ko);
            #pragma unroll
            for (int j = 0; j < 4; j++)
                bf[j] = *(const s16x8*)(Bs + (wn + j * 16 + ln15) * LDT + ko);
            #pragma unroll
            for (int i = 0; i < 4; i++)
                #pragma unroll
                for (int j = 0; j < 4; j++)
                    acc[i][j] = __builtin_amdgcn_mfma_f32_16x16x32_bf16(af[i], bf[j], acc[i][j], 0, 0, 0);
        }
        __syncthreads();
    }

    // ---- fused epilogue: JSD terms, masked ----
    const int num_nodes = nn_lens[0];
    const int len_b     = nn_lens[1 + b_idx];
    const float LOG2f = 0.6931471805599453f;

    float pos_sum = 0.f, neg_sum = 0.f;
    #pragma unroll
    for (int i = 0; i < 4; i++) {
        #pragma unroll
        for (int r = 0; r < 4; r++) {
            const int s = s_base + wm + i * 16 + quad * 4 + r;       // C/D row = quad*4+reg
            const bool valid = (s < len_b);
            #pragma unroll
            for (int j = 0; j < 4; j++) {
                const int n = wn + j * 16 + ln15;                    // C/D col = lane&15
                const float x = acc[i][j][r];
                const float e  = __expf(-fabsf(x));
                const float sp = fmaxf(-x, 0.f) + __logf(1.f + e);   // softplus(-x), stable
                if (valid) {
                    if (n == b_idx) pos_sum += LOG2f - sp;           // Ep
                    else            neg_sum += sp + x - LOG2f;       // Eq
                }
            }
        }
    }

    // block reduction + one atomic per block
    #pragma unroll
    for (int off = 32; off > 0; off >>= 1) {
        pos_sum += __shfl_down(pos_sum, off, 64);
        neg_sum += __shfl_down(neg_sum, off, 64);
    }
    __syncthreads();                     // LDS tiles no longer needed
    __shared__ float red[8];
    if (lane == 0) { red[wid] = pos_sum; red[4 + wid] = neg_sum; }
    __syncthreads();
    if (tid == 0) {
        const float p  = red[0] + red[1] + red[2] + red[3];
        const float ng = red[4] + red[5] + red[6] + red[7];
        const float nn = (float)num_nodes;
        atomicAdd(out, ng / (nn * (float)(BB - 1)) - p / nn);
    }
}

extern "C" void kernel_launch(void* const* d_in, const int* in_sizes, int n_in,
                              void* d_out, int out_size, void* d_ws, size_t ws_size,
                              hipStream_t stream) {
    const float* seq  = (const float*)d_in[0];   // [128,1024,1024] fp32
    const float* ctx  = (const float*)d_in[1];   // [128,1024] fp32
    const int*   mask = (const int*)d_in[2];     // [128,1024] int32
    int* nn_lens = (int*)d_ws;                            // [0]=num_nodes, [1..128]=lens
    unsigned short* Bbf = (unsigned short*)((char*)d_ws + 1024);  // 256 KB bf16 ctx

    hipMemsetAsync(d_out, 0, sizeof(float), stream);
    hipMemsetAsync(d_ws, 0, sizeof(int), stream);

    lens_kernel<<<BB, 256, 0, stream>>>(mask, nn_lens);
    bconv_kernel<<<BB, 256, 0, stream>>>(ctx, Bbf);
    mi_kernel<<<(BB * SS) / MT, 256, 0, stream>>>(seq, Bbf, nn_lens, (float*)d_out);
}